// Round 11
// baseline (87.732 us; speedup 1.0000x reference)
//
#include <hip/hip_runtime.h>
#include <math.h>

#define NS 512
#define DE 512
#define NCL 5
#define NBLK 256

// ws layout: dotA[256*512] | dotB[256*512] | dg[512] | ctrl[4]
// ctrl words: [0]=gsum(f32) [1]=gnz [2]=ticket [3]=spare  (zeroed by memset)

// ---------------------------------------------------------------------------
// K1: raw dot rows. Block b: dotA[b][j] = <row_j, row_b>,
//     dotB[b][j] = <row_j, row_{b+256}>; block 0 also writes dg[j] = <row_j,row_j>.
//     Coalesced 16-lane-per-row scheme; anchor fragments in VGPRs
//     (launch_bounds(512,2) -> 256-VGPR budget, room to prefetch).
// ---------------------------------------------------------------------------
__global__ __launch_bounds__(512, 2) void k_dots(const float* __restrict__ pred,
                                                 float* __restrict__ dotA,
                                                 float* __restrict__ dotB,
                                                 float* __restrict__ dg) {
    const int b = blockIdx.x;
    const int tid = threadIdx.x;
    const int iA = b, iB = b + 256;

    const int w = tid >> 6, lane = tid & 63;
    const int g = lane >> 4, s = lane & 15;

    const float4* pA = (const float4*)&pred[(size_t)iA * DE];
    const float4* pB = (const float4*)&pred[(size_t)iB * DE];
    float4 fA[8], fB[8];
#pragma unroll
    for (int p = 0; p < 8; p++) { fA[p] = pA[p * 16 + s]; fB[p] = pB[p * 16 + s]; }

#pragma unroll 4
    for (int t = 0; t < 16; t++) {
        const int j = w * 64 + t * 4 + g;
        const float4* rj = (const float4*)&pred[(size_t)j * DE];
        float4 x[8];
#pragma unroll
        for (int p = 0; p < 8; p++) x[p] = rj[p * 16 + s];   // 8 independent loads
        float aA = 0.0f, aB = 0.0f, aS = 0.0f;
#pragma unroll
        for (int p = 0; p < 8; p++) {
            aA = fmaf(x[p].x, fA[p].x, aA); aA = fmaf(x[p].y, fA[p].y, aA);
            aA = fmaf(x[p].z, fA[p].z, aA); aA = fmaf(x[p].w, fA[p].w, aA);
            aB = fmaf(x[p].x, fB[p].x, aB); aB = fmaf(x[p].y, fB[p].y, aB);
            aB = fmaf(x[p].z, fB[p].z, aB); aB = fmaf(x[p].w, fB[p].w, aB);
            aS = fmaf(x[p].x, x[p].x, aS);  aS = fmaf(x[p].y, x[p].y, aS);
            aS = fmaf(x[p].z, x[p].z, aS);  aS = fmaf(x[p].w, x[p].w, aS);
        }
#pragma unroll
        for (int m = 1; m <= 8; m <<= 1) {
            aA += __shfl_xor(aA, m);
            aB += __shfl_xor(aB, m);
            aS += __shfl_xor(aS, m);
        }
        if (s == 0) {
            dotA[(size_t)b * NS + j] = aA;
            dotB[(size_t)b * NS + j] = aB;
            if (b == 0) dg[j] = aS;
        }
    }
}

// ---------------------------------------------------------------------------
// K2: loss for anchors iA=b, iB=b+256 from raw dot rows + diag.
//     R10-proven loss phase + ticket finalize.
// ---------------------------------------------------------------------------
__global__ __launch_bounds__(512) void k_loss(const float* __restrict__ dotA,
                                              const float* __restrict__ dotB,
                                              const float* __restrict__ dg,
                                              const int* __restrict__ target,
                                              const float* __restrict__ draw,
                                              unsigned int* __restrict__ ctrl,
                                              float* __restrict__ out) {
    const int b = blockIdx.x;
    const int tid = threadIdx.x;
    const int iA = b, iB = b + 256;

    __shared__ float  rn_s[NS];
    __shared__ float  ckA[NS], ckB[NS];
    __shared__ float4 v4sA[NS / 4], v4sB[NS / 4];
    __shared__ int    pkA[NS], pkB[NS];
    __shared__ float  spart[NS * 17];
    __shared__ float  redf[512];
    __shared__ int    redi[512];
    __shared__ unsigned int pcA, pcB;

    float* gsum = (float*)ctrl;
    unsigned int* gnz    = ctrl + 1;
    unsigned int* ticket = ctrl + 2;

    if (tid == 0) { pcA = 0u; pcB = 0u; }

    const int j = tid;
    const float da = dotA[(size_t)b * NS + j];
    const float db = dotB[(size_t)b * NS + j];
    const float ns = dg[j];
    const float rnj = 1.0f / fmaxf(sqrtf(ns), 1e-8f);
    rn_s[j] = rnj;

    float cp[NCL];
    cp[0] = 0.0f;
#pragma unroll
    for (int c = 0; c < NCL - 1; c++) cp[c + 1] = cp[c] + log1pf(expf(draw[c]));
    const int tiA = target[iA], tiB = target[iB];
    const float cpA = cp[tiA], cpB = cp[tiB];
    const int tj = target[j];
    const float cpj = cp[tj];
    __syncthreads();

    const float rniA = rn_s[iA], rniB = rn_s[iB];
    {   // anchor A
        float c0 = da * rniA * rnj;
        bool n0 = (tj != tiA);
        ckA[j] = c0;
        ((float*)v4sA)[j] = n0 ? (c0 + fabsf(cpA - cpj)) : -1e30f;
        if (!n0 && j != iA) pkA[atomicAdd(&pcA, 1u)] = j;
        redi[tid] = (n0 ? 1 : 0);
    }
    {   // anchor B (negcounts packed: A low 16, B high 16)
        float c0 = db * rniB * rnj;
        bool n0 = (tj != tiB);
        ckB[j] = c0;
        ((float*)v4sB)[j] = n0 ? (c0 + fabsf(cpB - cpj)) : -1e30f;
        if (!n0 && j != iB) pkB[atomicAdd(&pcB, 1u)] = j;
        redi[tid] += (n0 ? 1 : 0) << 16;
    }
    __syncthreads();
    for (int s2 = 256; s2 > 0; s2 >>= 1) {
        if (tid < s2) redi[tid] += redi[tid + s2];
        __syncthreads();
    }
    const int negA = redi[0] & 0xffff;
    const int negB = redi[0] >> 16;
    const unsigned int nposA = pcA, nposB = pcB;
    __syncthreads();

    const int kl = tid & 31, jc = tid >> 5;
    const float denA = (float)(negA > 1 ? negA : 1);
    const float denB = (float)(negB > 1 ? negB : 1);
    float contrib = 0.0f;
    int nzc = 0;

    {   // anchor A
        float4 vj[8];
#pragma unroll
        for (int t = 0; t < 8; t++) vj[t] = v4sA[jc * 8 + t];
        for (unsigned int p = kl; p < nposA; p += 32) {
            const float ckp = ckA[pkA[p]];
            float s0 = 0.0f, s1 = 0.0f;
#pragma unroll
            for (int t = 0; t < 8; t++) {
                float4 wv = vj[t];
                s0 += fmaxf(wv.x - ckp, 0.0f) + fmaxf(wv.y - ckp, 0.0f);
                s1 += fmaxf(wv.z - ckp, 0.0f) + fmaxf(wv.w - ckp, 0.0f);
            }
            spart[p * 17 + jc] = s0 + s1;
        }
        __syncthreads();
        for (unsigned int p = tid; p < nposA; p += 512) {
            float s0 = 0.0f;
#pragma unroll
            for (int q = 0; q < 16; q++) s0 += spart[p * 17 + q];
            contrib += s0 / denA;
            if (s0 != 0.0f) nzc++;
        }
        __syncthreads();
    }
    {   // anchor B
        float4 vj[8];
#pragma unroll
        for (int t = 0; t < 8; t++) vj[t] = v4sB[jc * 8 + t];
        for (unsigned int p = kl; p < nposB; p += 32) {
            const float ckp = ckB[pkB[p]];
            float s0 = 0.0f, s1 = 0.0f;
#pragma unroll
            for (int t = 0; t < 8; t++) {
                float4 wv = vj[t];
                s0 += fmaxf(wv.x - ckp, 0.0f) + fmaxf(wv.y - ckp, 0.0f);
                s1 += fmaxf(wv.z - ckp, 0.0f) + fmaxf(wv.w - ckp, 0.0f);
            }
            spart[p * 17 + jc] = s0 + s1;
        }
        __syncthreads();
        for (unsigned int p = tid; p < nposB; p += 512) {
            float s0 = 0.0f;
#pragma unroll
            for (int q = 0; q < 16; q++) s0 += spart[p * 17 + q];
            contrib += s0 / denB;
            if (s0 != 0.0f) nzc++;
        }
    }

    redf[tid] = contrib;
    redi[tid] = nzc;
    __syncthreads();
    for (int s2 = 256; s2 > 0; s2 >>= 1) {
        if (tid < s2) { redf[tid] += redf[tid + s2]; redi[tid] += redi[tid + s2]; }
        __syncthreads();
    }
    if (tid == 0) {
        if (redf[0] != 0.0f || redi[0] != 0) {
            atomicAdd(gsum, redf[0]);
            atomicAdd(gnz, (unsigned int)redi[0]);
        }
        __threadfence();
        unsigned int t = atomicAdd(ticket, 1u);
        if (t == (unsigned int)(NBLK - 1)) {
            float s0 = atomicAdd(gsum, 0.0f);
            unsigned int n = atomicAdd(gnz, 0u);
            out[0] = s0 / (float)(n > 1u ? n : 1u);
        }
    }
}

extern "C" void kernel_launch(void* const* d_in, const int* in_sizes, int n_in,
                              void* d_out, int out_size, void* d_ws, size_t ws_size,
                              hipStream_t stream) {
    const float* pred   = (const float*)d_in[0];
    const float* draw   = (const float*)d_in[1];
    const int*   target = (const int*)d_in[2];
    float* out = (float*)d_out;

    float* ws   = (float*)d_ws;
    float* dotA = ws;                             // 256*512 floats
    float* dotB = ws + NBLK * NS;                 // 256*512 floats
    float* dg   = ws + 2 * NBLK * NS;             // 512 floats
    unsigned int* ctrl = (unsigned int*)(dg + NS);

    hipMemsetAsync(ctrl, 0, 4 * sizeof(unsigned int), stream);
    hipLaunchKernelGGL(k_dots, dim3(NBLK), dim3(512), 0, stream, pred, dotA, dotB, dg);
    hipLaunchKernelGGL(k_loss, dim3(NBLK), dim3(512), 0, stream,
                       dotA, dotB, dg, target, draw, ctrl, out);
}